// Round 1
// baseline (249.958 us; speedup 1.0000x reference)
//
#include <hip/hip_runtime.h>

#define ALPHA 0.90483741803595957f

// ---------------------------------------------------------------------------
// K0: fold avgpool into conv kernels.
// W1eff[oc][ch][u][v] (4x2x8x8): conv1 5x5 pad2 + pool4  => 8x8 stride-4 conv
// W2eff[oc][ch][u][v] (8x4x4x4): conv2 3x3 pad1 + pool2  => 4x4 stride-2 conv
// ---------------------------------------------------------------------------
__global__ void prep_weights(const float* __restrict__ w1, const float* __restrict__ w2,
                             float* __restrict__ w1e, float* __restrict__ w2e) {
    int idx = blockIdx.x * 256 + threadIdx.x;
    if (idx < 512) {
        int v = idx & 7, u = (idx >> 3) & 7, ch = (idx >> 6) & 1, oc = idx >> 7;
        float s = 0.f;
        for (int a = 0; a < 5; ++a) {
            int i = u - a; if (i < 0 || i > 3) continue;
            for (int b = 0; b < 5; ++b) {
                int j = v - b; if (j < 0 || j > 3) continue;
                s += w1[((oc * 2 + ch) * 5 + a) * 5 + b];
            }
        }
        w1e[idx] = s * (1.f / 16.f);
    } else if (idx < 1024) {
        int k = idx - 512;
        int v = k & 3, u = (k >> 2) & 3, ch = (k >> 4) & 3, oc = k >> 6;
        float s = 0.f;
        for (int a = 0; a < 3; ++a) {
            int i = u - a; if (i < 0 || i > 1) continue;
            for (int b = 0; b < 3; ++b) {
                int j = v - b; if (j < 0 || j > 1) continue;
                s += w2[((oc * 4 + ch) * 3 + a) * 3 + b];
            }
        }
        w2e[k] = s * 0.25f;
    }
}

// ---------------------------------------------------------------------------
// K1: conv1 + pool4 via 8x8/stride-4 effective kernel.  (unchanged)
// ---------------------------------------------------------------------------
__global__ __launch_bounds__(256) void conv1_pool(const float* __restrict__ x,
                                                  const float* __restrict__ w1e,
                                                  float* __restrict__ y1) {
    __shared__ __align__(16) float tile[4][2][36][36];  // 41472 B
    int tid = threadIdx.x;

    float4* t4 = (float4*)&tile[0][0][0][0];
    #pragma unroll
    for (int k = 0; k < 11; ++k) {
        int i = tid + k * 256;
        if (i < 2592) t4[i] = make_float4(0.f, 0.f, 0.f, 0.f);
    }
    __syncthreads();

    int li = tid >> 6, pos = tid & 63;
    long gi = (long)blockIdx.x * 4 + li;            // bt index, < 12800
    const float* src = x + gi * 2048;               // 2ch*32*32
    #pragma unroll
    for (int k = 0; k < 8; ++k) {
        int e = k * 256 + pos * 4;                  // 16B-aligned
        float4 d = *(const float4*)(src + e);
        int ch = e >> 10, rem = e & 1023, r = rem >> 5, c = rem & 31;
        float* dst = &tile[li][ch][r + 2][c + 2];
        dst[0] = d.x; dst[1] = d.y; dst[2] = d.z; dst[3] = d.w;
    }
    __syncthreads();

    int p = pos >> 3, q = pos & 7;
    float acc0 = 0.f, acc1 = 0.f, acc2 = 0.f, acc3 = 0.f;
    #pragma unroll
    for (int ch = 0; ch < 2; ++ch) {
        #pragma unroll
        for (int r = 0; r < 8; ++r) {
            const float* row = &tile[li][ch][4 * p + r][4 * q];  // 16B aligned
            float4 a = *(const float4*)row;
            float4 b = *(const float4*)(row + 4);
            float in[8] = {a.x, a.y, a.z, a.w, b.x, b.y, b.z, b.w};
            #pragma unroll
            for (int c = 0; c < 8; ++c) {
                float xi = in[c];
                acc0 += w1e[((0 * 2 + ch) * 8 + r) * 8 + c] * xi;  // uniform -> s_load
                acc1 += w1e[((1 * 2 + ch) * 8 + r) * 8 + c] * xi;
                acc2 += w1e[((2 * 2 + ch) * 8 + r) * 8 + c] * xi;
                acc3 += w1e[((3 * 2 + ch) * 8 + r) * 8 + c] * xi;
            }
        }
    }
    float* dst = y1 + gi * 256 + pos;   // [bt][oc][p][q]
    dst[0] = acc0; dst[64] = acc1; dst[128] = acc2; dst[192] = acc3;
}

// ---------------------------------------------------------------------------
// K2 (fused tail): scan1 + conv2/pool2 + scan2 + linear, one block per b.
// 256 threads: tid = stage-1 feature f (ch,r,c). Scan states live in regs;
// spikes pass through a 4x10x10 padded LDS tile each timestep; threads <128
// compute conv2 (same FMA chain order as the old conv2_pool kernel so the
// spike-generating sums stay bitwise identical), scan2 in regs, linear via
// wave shfl reduction.  2 barriers per timestep.
// ---------------------------------------------------------------------------
__global__ __launch_bounds__(256) void fused_tail(const float* __restrict__ y1,
                                                  const float* __restrict__ w2e,
                                                  const float* __restrict__ lw,
                                                  float* __restrict__ out) {
    __shared__ float tile[4][10][10];   // 400 floats, zero border = conv pad
    __shared__ float red[2][2];
    int tid = threadIdx.x;
    int b = blockIdx.x;

    for (int i = tid; i < 400; i += 256) ((float*)tile)[i] = 0.f;

    // stage-1 mapping: f = tid = ch*64 + r*8 + c
    int ch1 = tid >> 6, r1 = (tid >> 3) & 7, c1 = tid & 7;
    float* tslot = &tile[ch1][r1 + 1][c1 + 1];

    // conv2 mapping (threads < 128): f2 = tid = oc*16 + p*4 + q
    int oc = tid >> 4, p = (tid >> 2) & 3, q = tid & 3;
    float wts[64];
    float lw0 = 0.f, lw1 = 0.f;
    if (tid < 128) {
        #pragma unroll
        for (int k = 0; k < 64; ++k) wts[k] = w2e[oc * 64 + k];
        lw0 = lw[tid];          // lin_w[0][f2]
        lw1 = lw[128 + tid];    // lin_w[1][f2]
    }
    const float* base = &tile[0][2 * p][2 * q];

    const float* src = y1 + (long)b * 100 * 256 + tid;
    float* outp = out + (long)b * 200;

    float cur = src[0];
    float nxt = src[256];
    float v1 = 0.f, v2 = 0.f, v1b = 0.f, v2b = 0.f;

    __syncthreads();   // tile zeros visible

    for (int t = 0; t < 100; ++t) {
        float nn = (t + 2 < 100) ? src[(t + 2) * 256] : 0.f;   // prefetch depth 2

        // stage-1 exp_leak + LIF (identical arithmetic to old scan1)
        v1 = ALPHA * v1 + cur;
        v2 = ALPHA * v2 + v1;
        float s = (v2 >= 1.f) ? 1.f : 0.f;
        v2 -= s;
        *tslot = s;
        __syncthreads();     // B1: spikes ready

        if (tid < 128) {
            // conv2 + pool2: 4x4/stride-2 effective kernel, padded tile.
            // FMA chain order (ch, r, c ascending) matches old conv2_pool.
            float acc = 0.f;
            #pragma unroll
            for (int ch = 0; ch < 4; ++ch) {
                #pragma unroll
                for (int r = 0; r < 4; ++r) {
                    const float* row = base + ch * 100 + r * 10;   // 8B aligned
                    float2 u = *(const float2*)row;
                    float2 w = *(const float2*)(row + 2);
                    acc += wts[ch * 16 + r * 4 + 0] * u.x;
                    acc += wts[ch * 16 + r * 4 + 1] * u.y;
                    acc += wts[ch * 16 + r * 4 + 2] * w.x;
                    acc += wts[ch * 16 + r * 4 + 3] * w.y;
                }
            }
            // stage-2 exp_leak + LIF (identical arithmetic to old scan2)
            v1b = ALPHA * v1b + acc;
            v2b = ALPHA * v2b + v1b;
            float s2 = (v2b >= 1.f) ? 1.f : 0.f;
            v2b -= s2;

            // linear: out[o] = sum_f s2[f] * lw[o][f]
            float a0 = s2 * lw0;
            float a1 = s2 * lw1;
            #pragma unroll
            for (int off = 32; off; off >>= 1) {
                a0 += __shfl_xor(a0, off);
                a1 += __shfl_xor(a1, off);
            }
            if ((tid & 63) == 0) { red[tid >> 6][0] = a0; red[tid >> 6][1] = a1; }
        }
        __syncthreads();     // B2: red ready; also fences tile for next t
        if (tid == 0) {
            float2 o2;
            o2.x = red[0][0] + red[1][0];
            o2.y = red[0][1] + red[1][1];
            *(float2*)(outp + t * 2) = o2;
        }
        cur = nxt; nxt = nn;
    }
}

extern "C" void kernel_launch(void* const* d_in, const int* in_sizes, int n_in,
                              void* d_out, int out_size, void* d_ws, size_t ws_size,
                              hipStream_t stream) {
    const float* x  = (const float*)d_in[0];   // [128,100,2,32,32]
    const float* w1 = (const float*)d_in[1];   // [4,2,5,5]
    const float* w2 = (const float*)d_in[2];   // [8,4,3,3]
    const float* lw = (const float*)d_in[3];   // [2,128]
    float* out = (float*)d_out;                // [128,100,2]

    float* ws   = (float*)d_ws;
    float* w1e  = ws;                 // 512 floats
    float* w2e  = ws + 512;           // 512 floats
    float* y1   = ws + 1024;          // 12800*256 = 3276800 floats

    prep_weights<<<4, 256, 0, stream>>>(w1, w2, w1e, w2e);
    conv1_pool<<<3200, 256, 0, stream>>>(x, w1e, y1);
    fused_tail<<<128, 256, 0, stream>>>(y1, w2e, lw, out);
}

// Round 2
// 215.884 us; speedup vs baseline: 1.1578x; 1.1578x over previous
//
#include <hip/hip_runtime.h>

#define ALPHA 0.90483741803595957f

// ---------------------------------------------------------------------------
// K0: fold avgpool into conv kernels.
// W1eff[oc][ch][u][v] (4x2x8x8): conv1 5x5 pad2 + pool4  => 8x8 stride-4 conv
// W2eff[oc][ch][u][v] (8x4x4x4): conv2 3x3 pad1 + pool2  => 4x4 stride-2 conv
// ---------------------------------------------------------------------------
__global__ void prep_weights(const float* __restrict__ w1, const float* __restrict__ w2,
                             float* __restrict__ w1e, float* __restrict__ w2e) {
    int idx = blockIdx.x * 256 + threadIdx.x;
    if (idx < 512) {
        int v = idx & 7, u = (idx >> 3) & 7, ch = (idx >> 6) & 1, oc = idx >> 7;
        float s = 0.f;
        for (int a = 0; a < 5; ++a) {
            int i = u - a; if (i < 0 || i > 3) continue;
            for (int b = 0; b < 5; ++b) {
                int j = v - b; if (j < 0 || j > 3) continue;
                s += w1[((oc * 2 + ch) * 5 + a) * 5 + b];
            }
        }
        w1e[idx] = s * (1.f / 16.f);
    } else if (idx < 1024) {
        int k = idx - 512;
        int v = k & 3, u = (k >> 2) & 3, ch = (k >> 4) & 3, oc = k >> 6;
        float s = 0.f;
        for (int a = 0; a < 3; ++a) {
            int i = u - a; if (i < 0 || i > 1) continue;
            for (int b = 0; b < 3; ++b) {
                int j = v - b; if (j < 0 || j > 1) continue;
                s += w2[((oc * 4 + ch) * 3 + a) * 3 + b];
            }
        }
        w2e[k] = s * 0.25f;
    }
}

// ---------------------------------------------------------------------------
// K1: conv1 + pool4 via 8x8/stride-4 effective kernel.  (unchanged)
// ---------------------------------------------------------------------------
__global__ __launch_bounds__(256) void conv1_pool(const float* __restrict__ x,
                                                  const float* __restrict__ w1e,
                                                  float* __restrict__ y1) {
    __shared__ __align__(16) float tile[4][2][36][36];  // 41472 B
    int tid = threadIdx.x;

    float4* t4 = (float4*)&tile[0][0][0][0];
    #pragma unroll
    for (int k = 0; k < 11; ++k) {
        int i = tid + k * 256;
        if (i < 2592) t4[i] = make_float4(0.f, 0.f, 0.f, 0.f);
    }
    __syncthreads();

    int li = tid >> 6, pos = tid & 63;
    long gi = (long)blockIdx.x * 4 + li;            // bt index, < 12800
    const float* src = x + gi * 2048;               // 2ch*32*32
    #pragma unroll
    for (int k = 0; k < 8; ++k) {
        int e = k * 256 + pos * 4;                  // 16B-aligned
        float4 d = *(const float4*)(src + e);
        int ch = e >> 10, rem = e & 1023, r = rem >> 5, c = rem & 31;
        float* dst = &tile[li][ch][r + 2][c + 2];
        dst[0] = d.x; dst[1] = d.y; dst[2] = d.z; dst[3] = d.w;
    }
    __syncthreads();

    int p = pos >> 3, q = pos & 7;
    float acc0 = 0.f, acc1 = 0.f, acc2 = 0.f, acc3 = 0.f;
    #pragma unroll
    for (int ch = 0; ch < 2; ++ch) {
        #pragma unroll
        for (int r = 0; r < 8; ++r) {
            const float* row = &tile[li][ch][4 * p + r][4 * q];  // 16B aligned
            float4 a = *(const float4*)row;
            float4 b = *(const float4*)(row + 4);
            float in[8] = {a.x, a.y, a.z, a.w, b.x, b.y, b.z, b.w};
            #pragma unroll
            for (int c = 0; c < 8; ++c) {
                float xi = in[c];
                acc0 += w1e[((0 * 2 + ch) * 8 + r) * 8 + c] * xi;  // uniform -> s_load
                acc1 += w1e[((1 * 2 + ch) * 8 + r) * 8 + c] * xi;
                acc2 += w1e[((2 * 2 + ch) * 8 + r) * 8 + c] * xi;
                acc3 += w1e[((3 * 2 + ch) * 8 + r) * 8 + c] * xi;
            }
        }
    }
    float* dst = y1 + gi * 256 + pos;   // [bt][oc][p][q]
    dst[0] = acc0; dst[64] = acc1; dst[128] = acc2; dst[192] = acc3;
}

// ---------------------------------------------------------------------------
// K2: fused scan1 + conv2/pool2 + scan2 for one b per 64-thread block (1 wave).
// Single wave => __syncthreads is just s_waitcnt (no s_barrier cost).
// Spike tile is channel-last [10][10][4] so a conv2 window row is 16
// contiguous floats (4x ds_read_b128). Two tile copies (B at odd quad offset
// +404 floats) cut read bank conflicts from 4-way to 2-way.
// Each lane: 4 stage-1 scan chains (f = 64k+lane), one float4 spike write per
// copy, 2 conv2 outputs (f2 = lane, lane+64: same window, oc and oc+4) with
// all 128 weights in VGPRs (__launch_bounds__(64,1)), 2 stage-2 scan chains.
// s2 spikes go to global; the linear layer is deferred to linear_out.
// FMA order for conv2 is (ch, rr, cc) ascending into a scalar acc — bitwise
// identical to the previous conv2_pool chain, so spike decisions are stable.
// ---------------------------------------------------------------------------
__global__ __launch_bounds__(64, 1) void fused_wave(const float* __restrict__ y1,
                                                    const float* __restrict__ w2e,
                                                    float* __restrict__ s2g) {
    __shared__ float tile[808];   // copy A @0 (400 floats), copy B @404 (quad 101, odd)
    int lane = threadIdx.x;
    int b = blockIdx.x;

    #pragma unroll
    for (int k = 0; k < 13; ++k) {
        int i = lane + k * 64;
        if (i < 808) tile[i] = 0.f;
    }

    // stage-1 mapping: f = 64k + lane -> (ch=k, r=lane>>3, c=lane&7)
    int r1 = lane >> 3, c1 = lane & 7;
    int posq = (r1 + 1) * 10 + (c1 + 1);           // position quad in tile
    float* wrA = &tile[posq * 4];
    float* wrB = &tile[404 + posq * 4];

    // conv2 mapping: f2a = lane -> (oc=lane>>4, p=(lane>>2)&3, q=lane&3); f2b = lane+64
    int oc = lane >> 4, p = (lane >> 2) & 3, q = lane & 3;

    // weights resident in VGPRs: wa/wb[ch*16 + rr*4 + cc]
    float wa[64], wb[64];
    #pragma unroll
    for (int k = 0; k < 16; ++k) {
        float4 ta = *(const float4*)(w2e + oc * 64 + k * 4);
        float4 tb = *(const float4*)(w2e + (oc + 4) * 64 + k * 4);
        wa[k * 4 + 0] = ta.x; wa[k * 4 + 1] = ta.y; wa[k * 4 + 2] = ta.z; wa[k * 4 + 3] = ta.w;
        wb[k * 4 + 0] = tb.x; wb[k * 4 + 1] = tb.y; wb[k * 4 + 2] = tb.z; wb[k * 4 + 3] = tb.w;
    }

    const float* rbase = &tile[((2 * p) * 10 + 2 * q) * 4];
    if (p & 1) rbase += 404;                       // odd-p groups read copy B

    const float* src = y1 + (long)b * 25600 + lane;   // y1[b][t][f], f = 64k+lane
    float* dst = s2g + (long)b * 100 * 128 + lane;    // s2[bt][f]

    float cur0 = src[0], cur1 = src[64], cur2 = src[128], cur3 = src[192];
    float v10 = 0.f, v20 = 0.f, v11 = 0.f, v21 = 0.f;
    float v12 = 0.f, v22 = 0.f, v13 = 0.f, v23 = 0.f;
    float w1a = 0.f, w2a = 0.f, w1b = 0.f, w2b = 0.f;   // stage-2 states

    __syncthreads();   // tile zeros visible (single wave: waitcnt only)

    for (int t = 0; t < 100; ++t) {
        // prefetch next timestep (clamped address keeps it in-bounds at t=99)
        const float* nsrc = src + (t < 99 ? (t + 1) * 256 : 0);
        float n0 = nsrc[0], n1 = nsrc[64], n2 = nsrc[128], n3 = nsrc[192];

        // stage-1 exp_leak + LIF (identical arithmetic to scan1)
        v10 = ALPHA * v10 + cur0; v20 = ALPHA * v20 + v10;
        float s0 = (v20 >= 1.f) ? 1.f : 0.f; v20 -= s0;
        v11 = ALPHA * v11 + cur1; v21 = ALPHA * v21 + v11;
        float s1 = (v21 >= 1.f) ? 1.f : 0.f; v21 -= s1;
        v12 = ALPHA * v12 + cur2; v22 = ALPHA * v22 + v12;
        float s2 = (v22 >= 1.f) ? 1.f : 0.f; v22 -= s2;
        v13 = ALPHA * v13 + cur3; v23 = ALPHA * v23 + v13;
        float s3 = (v23 >= 1.f) ? 1.f : 0.f; v23 -= s3;

        float4 sp = make_float4(s0, s1, s2, s3);       // channel-last (ch = k)
        *(float4*)wrA = sp;
        *(float4*)wrB = sp;
        __syncthreads();   // lgkmcnt(0): spikes visible to this wave

        // conv2 window: 16 aligned float4 loads (rows rr, positions cc, ch-vec)
        float qv[64];
        #pragma unroll
        for (int rr = 0; rr < 4; ++rr) {
            #pragma unroll
            for (int cc = 0; cc < 4; ++cc) {
                float4 tq = *(const float4*)(rbase + rr * 40 + cc * 4);
                int o = (rr * 4 + cc) * 4;
                qv[o + 0] = tq.x; qv[o + 1] = tq.y; qv[o + 2] = tq.z; qv[o + 3] = tq.w;
            }
        }

        float acca = 0.f, accb = 0.f;
        #pragma unroll
        for (int ch = 0; ch < 4; ++ch)
            #pragma unroll
            for (int rr = 0; rr < 4; ++rr)
                #pragma unroll
                for (int cc = 0; cc < 4; ++cc) {
                    float xv = qv[(rr * 4 + cc) * 4 + ch];
                    acca += wa[ch * 16 + rr * 4 + cc] * xv;
                    accb += wb[ch * 16 + rr * 4 + cc] * xv;
                }

        // stage-2 exp_leak + LIF (identical arithmetic to scan2)
        w1a = ALPHA * w1a + acca; w2a = ALPHA * w2a + w1a;
        float sa = (w2a >= 1.f) ? 1.f : 0.f; w2a -= sa;
        w1b = ALPHA * w1b + accb; w2b = ALPHA * w2b + w1b;
        float sb = (w2b >= 1.f) ? 1.f : 0.f; w2b -= sb;

        dst[t * 128] = sa;
        dst[t * 128 + 64] = sb;

        __syncthreads();   // reads drained before next iteration's spike writes
        cur0 = n0; cur1 = n1; cur2 = n2; cur3 = n3;
    }
}

// ---------------------------------------------------------------------------
// K3: out[bt][o] = sum_f s2[bt][f] * lin_w[o][f].  One wave per bt.
// ---------------------------------------------------------------------------
__global__ __launch_bounds__(256) void linear_out(const float* __restrict__ s2,
                                                  const float* __restrict__ lw,
                                                  float* __restrict__ out) {
    int tid = threadIdx.x;
    long bt = (long)blockIdx.x * 4 + (tid >> 6);
    int lane = tid & 63;
    float2 v = *(const float2*)(s2 + bt * 128 + lane * 2);
    float w00 = lw[lane * 2], w01 = lw[lane * 2 + 1];
    float w10 = lw[128 + lane * 2], w11 = lw[128 + lane * 2 + 1];
    float a0 = v.x * w00 + v.y * w01;
    float a1 = v.x * w10 + v.y * w11;
    #pragma unroll
    for (int off = 32; off; off >>= 1) {
        a0 += __shfl_down(a0, off);
        a1 += __shfl_down(a1, off);
    }
    if (lane == 0) { out[bt * 2] = a0; out[bt * 2 + 1] = a1; }
}

extern "C" void kernel_launch(void* const* d_in, const int* in_sizes, int n_in,
                              void* d_out, int out_size, void* d_ws, size_t ws_size,
                              hipStream_t stream) {
    const float* x  = (const float*)d_in[0];   // [128,100,2,32,32]
    const float* w1 = (const float*)d_in[1];   // [4,2,5,5]
    const float* w2 = (const float*)d_in[2];   // [8,4,3,3]
    const float* lw = (const float*)d_in[3];   // [2,128]
    float* out = (float*)d_out;                // [128,100,2]

    float* ws   = (float*)d_ws;
    float* w1e  = ws;                          // 512 floats
    float* w2e  = ws + 512;                    // 512 floats
    float* y1   = ws + 1024;                   // 12800*256 floats = 13.1 MB
    float* s2g  = y1 + 3276800;                // 12800*128 floats = 6.55 MB

    prep_weights<<<4, 256, 0, stream>>>(w1, w2, w1e, w2e);
    conv1_pool<<<3200, 256, 0, stream>>>(x, w1e, y1);
    fused_wave<<<128, 64, 0, stream>>>(y1, w2e, s2g);
    linear_out<<<3200, 256, 0, stream>>>(s2g, lw, out);
}

// Round 3
// 212.165 us; speedup vs baseline: 1.1781x; 1.0175x over previous
//
#include <hip/hip_runtime.h>

#define ALPHA 0.90483741803595957f

// ---------------------------------------------------------------------------
// K0: fold avgpool into conv kernels.
// W1eff[oc][ch][u][v] (4x2x8x8): conv1 5x5 pad2 + pool4  => 8x8 stride-4 conv
// W2eff[oc][ch][u][v] (8x4x4x4): conv2 3x3 pad1 + pool2  => 4x4 stride-2 conv
// ---------------------------------------------------------------------------
__global__ void prep_weights(const float* __restrict__ w1, const float* __restrict__ w2,
                             float* __restrict__ w1e, float* __restrict__ w2e) {
    int idx = blockIdx.x * 256 + threadIdx.x;
    if (idx < 512) {
        int v = idx & 7, u = (idx >> 3) & 7, ch = (idx >> 6) & 1, oc = idx >> 7;
        float s = 0.f;
        for (int a = 0; a < 5; ++a) {
            int i = u - a; if (i < 0 || i > 3) continue;
            for (int b = 0; b < 5; ++b) {
                int j = v - b; if (j < 0 || j > 3) continue;
                s += w1[((oc * 2 + ch) * 5 + a) * 5 + b];
            }
        }
        w1e[idx] = s * (1.f / 16.f);
    } else if (idx < 1024) {
        int k = idx - 512;
        int v = k & 3, u = (k >> 2) & 3, ch = (k >> 4) & 3, oc = k >> 6;
        float s = 0.f;
        for (int a = 0; a < 3; ++a) {
            int i = u - a; if (i < 0 || i > 1) continue;
            for (int b = 0; b < 3; ++b) {
                int j = v - b; if (j < 0 || j > 1) continue;
                s += w2[((oc * 4 + ch) * 3 + a) * 3 + b];
            }
        }
        w2e[k] = s * 0.25f;
    }
}

// ---------------------------------------------------------------------------
// K1: conv1 + pool4 via 8x8/stride-4 effective kernel.  (unchanged)
// ---------------------------------------------------------------------------
__global__ __launch_bounds__(256) void conv1_pool(const float* __restrict__ x,
                                                  const float* __restrict__ w1e,
                                                  float* __restrict__ y1) {
    __shared__ __align__(16) float tile[4][2][36][36];  // 41472 B
    int tid = threadIdx.x;

    float4* t4 = (float4*)&tile[0][0][0][0];
    #pragma unroll
    for (int k = 0; k < 11; ++k) {
        int i = tid + k * 256;
        if (i < 2592) t4[i] = make_float4(0.f, 0.f, 0.f, 0.f);
    }
    __syncthreads();

    int li = tid >> 6, pos = tid & 63;
    long gi = (long)blockIdx.x * 4 + li;            // bt index, < 12800
    const float* src = x + gi * 2048;               // 2ch*32*32
    #pragma unroll
    for (int k = 0; k < 8; ++k) {
        int e = k * 256 + pos * 4;                  // 16B-aligned
        float4 d = *(const float4*)(src + e);
        int ch = e >> 10, rem = e & 1023, r = rem >> 5, c = rem & 31;
        float* dst = &tile[li][ch][r + 2][c + 2];
        dst[0] = d.x; dst[1] = d.y; dst[2] = d.z; dst[3] = d.w;
    }
    __syncthreads();

    int p = pos >> 3, q = pos & 7;
    float acc0 = 0.f, acc1 = 0.f, acc2 = 0.f, acc3 = 0.f;
    #pragma unroll
    for (int ch = 0; ch < 2; ++ch) {
        #pragma unroll
        for (int r = 0; r < 8; ++r) {
            const float* row = &tile[li][ch][4 * p + r][4 * q];  // 16B aligned
            float4 a = *(const float4*)row;
            float4 b = *(const float4*)(row + 4);
            float in[8] = {a.x, a.y, a.z, a.w, b.x, b.y, b.z, b.w};
            #pragma unroll
            for (int c = 0; c < 8; ++c) {
                float xi = in[c];
                acc0 += w1e[((0 * 2 + ch) * 8 + r) * 8 + c] * xi;  // uniform -> s_load
                acc1 += w1e[((1 * 2 + ch) * 8 + r) * 8 + c] * xi;
                acc2 += w1e[((2 * 2 + ch) * 8 + r) * 8 + c] * xi;
                acc3 += w1e[((3 * 2 + ch) * 8 + r) * 8 + c] * xi;
            }
        }
    }
    float* dst = y1 + gi * 256 + pos;   // [bt][oc][p][q]
    dst[0] = acc0; dst[64] = acc1; dst[128] = acc2; dst[192] = acc3;
}

// ---------------------------------------------------------------------------
// K2: fully fused scan1 + conv2/pool2 + scan2 + linear. One wave per b.
// NO __syncthreads in the loop: a single wave's DS ops execute in order, so
// write->read through LDS needs no barrier, and the compiler's counted
// lgkmcnt before FMA use is the only wait. This keeps vmcnt un-drained, so
// the t+2 global prefetch actually overlaps compute.
// t-loop unrolled x2 with two NAMED LDS tiles (tEv/tOd) so consecutive
// timesteps have no LDS WAR hazard and the scheduler can slide body-B's
// ds_reads under body-A's FMA chain.
// conv2 FMA chain order is (ch,rr,cc) ascending into a scalar acc — bitwise
// identical to all previous rounds, so spike decisions are stable.
// Linear layer folded in: per pair of timesteps, 4 xor-shuffle reductions in
// one trailing divergent region; s2 spikes never touch global memory.
// ---------------------------------------------------------------------------
__global__ __launch_bounds__(64, 1) void fused_wave(const float* __restrict__ y1,
                                                    const float* __restrict__ w2e,
                                                    const float* __restrict__ lw,
                                                    float* __restrict__ out) {
    __shared__ float tEv[808];   // even t: copy A @0, copy B @404 (odd quad offset)
    __shared__ float tOd[808];   // odd  t: same layout
    int lane = threadIdx.x;
    int b = blockIdx.x;

    #pragma unroll
    for (int k = 0; k < 13; ++k) {
        int i = lane + k * 64;
        if (i < 808) { tEv[i] = 0.f; tOd[i] = 0.f; }
    }

    // stage-1 mapping: f = 64k + lane -> (ch=k, r=lane>>3, c=lane&7)
    int r1 = lane >> 3, c1 = lane & 7;
    int posq = ((r1 + 1) * 10 + (c1 + 1)) * 4;
    float* wrE0 = &tEv[posq];
    float* wrE1 = &tEv[404 + posq];
    float* wrO0 = &tOd[posq];
    float* wrO1 = &tOd[404 + posq];

    // conv2 mapping: f2a = lane -> (oc=lane>>4, p=(lane>>2)&3, q=lane&3); f2b = lane+64
    int oc = lane >> 4, p = (lane >> 2) & 3, q = lane & 3;

    // conv2 weights resident in VGPRs
    float wa[64], wb[64];
    #pragma unroll
    for (int k = 0; k < 16; ++k) {
        float4 ta = *(const float4*)(w2e + oc * 64 + k * 4);
        float4 tb = *(const float4*)(w2e + (oc + 4) * 64 + k * 4);
        wa[k * 4 + 0] = ta.x; wa[k * 4 + 1] = ta.y; wa[k * 4 + 2] = ta.z; wa[k * 4 + 3] = ta.w;
        wb[k * 4 + 0] = tb.x; wb[k * 4 + 1] = tb.y; wb[k * 4 + 2] = tb.z; wb[k * 4 + 3] = tb.w;
    }

    int rbq = ((2 * p) * 10 + 2 * q) * 4 + ((p & 1) ? 404 : 0);
    const float* rbE = &tEv[rbq];
    const float* rbO = &tOd[rbq];

    // linear weights: outputs f2a=lane, f2b=lane+64
    float lw0a = lw[lane],       lw0b = lw[lane + 64];
    float lw1a = lw[lane + 128], lw1b = lw[lane + 192];

    const float* src = y1 + (long)b * 25600 + lane;   // y1[b][t][f], f = 64k+lane
    float* outp = out + (long)b * 200;

    float cur0 = src[0],   cur1 = src[64],  cur2 = src[128], cur3 = src[192];
    float nx0  = src[256], nx1  = src[320], nx2  = src[384], nx3  = src[448];
    float v10 = 0.f, v20 = 0.f, v11 = 0.f, v21 = 0.f;
    float v12 = 0.f, v22 = 0.f, v13 = 0.f, v23 = 0.f;
    float w1a = 0.f, w2a = 0.f, w1b = 0.f, w2b = 0.f;

    for (int tt = 0; tt < 50; ++tt) {
        int tA = 2 * tt;
        // ================= body A (even t, tile tEv) =================
        const float* nsA = src + (tA + 2 < 100 ? (tA + 2) * 256 : 0);
        float pA0 = nsA[0], pA1 = nsA[64], pA2 = nsA[128], pA3 = nsA[192];

        v10 = ALPHA * v10 + cur0; v20 = ALPHA * v20 + v10;
        float sA0 = (v20 >= 1.f) ? 1.f : 0.f; v20 -= sA0;
        v11 = ALPHA * v11 + cur1; v21 = ALPHA * v21 + v11;
        float sA1 = (v21 >= 1.f) ? 1.f : 0.f; v21 -= sA1;
        v12 = ALPHA * v12 + cur2; v22 = ALPHA * v22 + v12;
        float sA2 = (v22 >= 1.f) ? 1.f : 0.f; v22 -= sA2;
        v13 = ALPHA * v13 + cur3; v23 = ALPHA * v23 + v13;
        float sA3 = (v23 >= 1.f) ? 1.f : 0.f; v23 -= sA3;

        float4 spA = make_float4(sA0, sA1, sA2, sA3);
        *(float4*)wrE0 = spA;
        *(float4*)wrE1 = spA;

        float qa[64];
        #pragma unroll
        for (int rr = 0; rr < 4; ++rr) {
            #pragma unroll
            for (int cc = 0; cc < 4; ++cc) {
                float4 tq = *(const float4*)(rbE + rr * 40 + cc * 4);
                int o = (rr * 4 + cc) * 4;
                qa[o + 0] = tq.x; qa[o + 1] = tq.y; qa[o + 2] = tq.z; qa[o + 3] = tq.w;
            }
        }
        float accaA = 0.f, accbA = 0.f;
        #pragma unroll
        for (int ch = 0; ch < 4; ++ch)
            #pragma unroll
            for (int rr = 0; rr < 4; ++rr)
                #pragma unroll
                for (int cc = 0; cc < 4; ++cc) {
                    float xv = qa[(rr * 4 + cc) * 4 + ch];
                    accaA += wa[ch * 16 + rr * 4 + cc] * xv;
                    accbA += wb[ch * 16 + rr * 4 + cc] * xv;
                }
        w1a = ALPHA * w1a + accaA; w2a = ALPHA * w2a + w1a;
        float saA = (w2a >= 1.f) ? 1.f : 0.f; w2a -= saA;
        w1b = ALPHA * w1b + accbA; w2b = ALPHA * w2b + w1b;
        float sbA = (w2b >= 1.f) ? 1.f : 0.f; w2b -= sbA;

        // ================= body B (odd t, tile tOd) =================
        int tB = tA + 1;
        const float* nsB = src + (tB + 2 < 100 ? (tB + 2) * 256 : 0);
        float pB0 = nsB[0], pB1 = nsB[64], pB2 = nsB[128], pB3 = nsB[192];

        v10 = ALPHA * v10 + nx0; v20 = ALPHA * v20 + v10;
        float sB0 = (v20 >= 1.f) ? 1.f : 0.f; v20 -= sB0;
        v11 = ALPHA * v11 + nx1; v21 = ALPHA * v21 + v11;
        float sB1 = (v21 >= 1.f) ? 1.f : 0.f; v21 -= sB1;
        v12 = ALPHA * v12 + nx2; v22 = ALPHA * v22 + v12;
        float sB2 = (v22 >= 1.f) ? 1.f : 0.f; v22 -= sB2;
        v13 = ALPHA * v13 + nx3; v23 = ALPHA * v23 + v13;
        float sB3 = (v23 >= 1.f) ? 1.f : 0.f; v23 -= sB3;

        float4 spB = make_float4(sB0, sB1, sB2, sB3);
        *(float4*)wrO0 = spB;
        *(float4*)wrO1 = spB;

        float qb[64];
        #pragma unroll
        for (int rr = 0; rr < 4; ++rr) {
            #pragma unroll
            for (int cc = 0; cc < 4; ++cc) {
                float4 tq = *(const float4*)(rbO + rr * 40 + cc * 4);
                int o = (rr * 4 + cc) * 4;
                qb[o + 0] = tq.x; qb[o + 1] = tq.y; qb[o + 2] = tq.z; qb[o + 3] = tq.w;
            }
        }
        float accaB = 0.f, accbB = 0.f;
        #pragma unroll
        for (int ch = 0; ch < 4; ++ch)
            #pragma unroll
            for (int rr = 0; rr < 4; ++rr)
                #pragma unroll
                for (int cc = 0; cc < 4; ++cc) {
                    float xv = qb[(rr * 4 + cc) * 4 + ch];
                    accaB += wa[ch * 16 + rr * 4 + cc] * xv;
                    accbB += wb[ch * 16 + rr * 4 + cc] * xv;
                }
        w1a = ALPHA * w1a + accaB; w2a = ALPHA * w2a + w1a;
        float saB = (w2a >= 1.f) ? 1.f : 0.f; w2a -= saB;
        w1b = ALPHA * w1b + accbB; w2b = ALPHA * w2b + w1b;
        float sbB = (w2b >= 1.f) ? 1.f : 0.f; w2b -= sbB;

        // ============ pair tail: linear reduce + store (one branch) ============
        float a0 = saA * lw0a + sbA * lw0b;
        float a1 = saA * lw1a + sbA * lw1b;
        float b0 = saB * lw0a + sbB * lw0b;
        float b1 = saB * lw1a + sbB * lw1b;
        #pragma unroll
        for (int off = 32; off; off >>= 1) {
            a0 += __shfl_xor(a0, off);
            a1 += __shfl_xor(a1, off);
            b0 += __shfl_xor(b0, off);
            b1 += __shfl_xor(b1, off);
        }
        if (lane == 0) {
            *(float2*)(outp + tA * 2) = make_float2(a0, a1);
            *(float2*)(outp + tB * 2) = make_float2(b0, b1);
        }

        cur0 = pA0; cur1 = pA1; cur2 = pA2; cur3 = pA3;
        nx0 = pB0; nx1 = pB1; nx2 = pB2; nx3 = pB3;
    }
}

extern "C" void kernel_launch(void* const* d_in, const int* in_sizes, int n_in,
                              void* d_out, int out_size, void* d_ws, size_t ws_size,
                              hipStream_t stream) {
    const float* x  = (const float*)d_in[0];   // [128,100,2,32,32]
    const float* w1 = (const float*)d_in[1];   // [4,2,5,5]
    const float* w2 = (const float*)d_in[2];   // [8,4,3,3]
    const float* lw = (const float*)d_in[3];   // [2,128]
    float* out = (float*)d_out;                // [128,100,2]

    float* ws   = (float*)d_ws;
    float* w1e  = ws;                          // 512 floats
    float* w2e  = ws + 512;                    // 512 floats
    float* y1   = ws + 1024;                   // 12800*256 floats = 13.1 MB

    prep_weights<<<4, 256, 0, stream>>>(w1, w2, w1e, w2e);
    conv1_pool<<<3200, 256, 0, stream>>>(x, w1e, y1);
    fused_wave<<<128, 64, 0, stream>>>(y1, w2e, lw, out);
}

// Round 4
// 211.608 us; speedup vs baseline: 1.1812x; 1.0026x over previous
//
#include <hip/hip_runtime.h>

#define ALPHA 0.90483741803595957f

// ---------------------------------------------------------------------------
// K0: fold avgpool into conv kernels.
// W1eff[oc][ch][u][v] (4x2x8x8): conv1 5x5 pad2 + pool4  => 8x8 stride-4 conv
// W2eff[oc][ch][u][v] (8x4x4x4): conv2 3x3 pad1 + pool2  => 4x4 stride-2 conv
// ---------------------------------------------------------------------------
__global__ void prep_weights(const float* __restrict__ w1, const float* __restrict__ w2,
                             float* __restrict__ w1e, float* __restrict__ w2e) {
    int idx = blockIdx.x * 256 + threadIdx.x;
    if (idx < 512) {
        int v = idx & 7, u = (idx >> 3) & 7, ch = (idx >> 6) & 1, oc = idx >> 7;
        float s = 0.f;
        for (int a = 0; a < 5; ++a) {
            int i = u - a; if (i < 0 || i > 3) continue;
            for (int b = 0; b < 5; ++b) {
                int j = v - b; if (j < 0 || j > 3) continue;
                s += w1[((oc * 2 + ch) * 5 + a) * 5 + b];
            }
        }
        w1e[idx] = s * (1.f / 16.f);
    } else if (idx < 1024) {
        int k = idx - 512;
        int v = k & 3, u = (k >> 2) & 3, ch = (k >> 4) & 3, oc = k >> 6;
        float s = 0.f;
        for (int a = 0; a < 3; ++a) {
            int i = u - a; if (i < 0 || i > 1) continue;
            for (int b = 0; b < 3; ++b) {
                int j = v - b; if (j < 0 || j > 1) continue;
                s += w2[((oc * 4 + ch) * 3 + a) * 3 + b];
            }
        }
        w2e[k] = s * 0.25f;
    }
}

// ---------------------------------------------------------------------------
// K1: conv1 + pool4 via 8x8/stride-4 effective kernel.  (unchanged, proven)
// ---------------------------------------------------------------------------
__global__ __launch_bounds__(256) void conv1_pool(const float* __restrict__ x,
                                                  const float* __restrict__ w1e,
                                                  float* __restrict__ y1) {
    __shared__ __align__(16) float tile[4][2][36][36];  // 41472 B
    int tid = threadIdx.x;

    float4* t4 = (float4*)&tile[0][0][0][0];
    #pragma unroll
    for (int k = 0; k < 11; ++k) {
        int i = tid + k * 256;
        if (i < 2592) t4[i] = make_float4(0.f, 0.f, 0.f, 0.f);
    }
    __syncthreads();

    int li = tid >> 6, pos = tid & 63;
    long gi = (long)blockIdx.x * 4 + li;            // bt index, < 12800
    const float* src = x + gi * 2048;               // 2ch*32*32
    #pragma unroll
    for (int k = 0; k < 8; ++k) {
        int e = k * 256 + pos * 4;                  // 16B-aligned
        float4 d = *(const float4*)(src + e);
        int ch = e >> 10, rem = e & 1023, r = rem >> 5, c = rem & 31;
        float* dst = &tile[li][ch][r + 2][c + 2];
        dst[0] = d.x; dst[1] = d.y; dst[2] = d.z; dst[3] = d.w;
    }
    __syncthreads();

    int p = pos >> 3, q = pos & 7;
    float acc0 = 0.f, acc1 = 0.f, acc2 = 0.f, acc3 = 0.f;
    #pragma unroll
    for (int ch = 0; ch < 2; ++ch) {
        #pragma unroll
        for (int r = 0; r < 8; ++r) {
            const float* row = &tile[li][ch][4 * p + r][4 * q];  // 16B aligned
            float4 a = *(const float4*)row;
            float4 b = *(const float4*)(row + 4);
            float in[8] = {a.x, a.y, a.z, a.w, b.x, b.y, b.z, b.w};
            #pragma unroll
            for (int c = 0; c < 8; ++c) {
                float xi = in[c];
                acc0 += w1e[((0 * 2 + ch) * 8 + r) * 8 + c] * xi;  // uniform -> s_load
                acc1 += w1e[((1 * 2 + ch) * 8 + r) * 8 + c] * xi;
                acc2 += w1e[((2 * 2 + ch) * 8 + r) * 8 + c] * xi;
                acc3 += w1e[((3 * 2 + ch) * 8 + r) * 8 + c] * xi;
            }
        }
    }
    float* dst = y1 + gi * 256 + pos;   // [bt][oc][p][q]
    dst[0] = acc0; dst[64] = acc1; dst[128] = acc2; dst[192] = acc3;
}

// ---------------------------------------------------------------------------
// K2: fused scan1 + conv2/pool2 + scan2 + linear, one wave per b, barrier-free.
// SOFTWARE-PIPELINED: conv2(t) consumes the spike tile written by scan1(t) one
// body EARLIER, so the LDS write->read latency is off the critical path.
// Body order per iteration i (tiles E=even t, O=odd t):
//   issue y1 prefetch (t=2i+5, 2i+6  -> consumed 2 iterations later)
//   read window(2i) from E        [written last iteration]
//   scan1(2i+1) -> write O
//   FMA conv(2i) + scan2 + spikes
//   read window(2i+1) from O      [write completed ~300 cyc ago]
//   scan1(2i+2) -> write E        [WAR on E: in-order DS pipe, reads already issued]
//   FMA conv(2i+1) + scan2 + spikes
//   linear xor-tree reduce + store (2i, 2i+1)
// All arithmetic chains bit-identical to previous rounds (scan1/scan2 chains,
// conv2 ch-major FMA order, same xor reduce tree) -> absmax stays 0.
// VGPR ~320 (wa+wb+qa+qb+pipeline) fits the 512 budget at (64,1): no spill.
// ---------------------------------------------------------------------------
__global__ __launch_bounds__(64, 1) void fused_wave(const float* __restrict__ y1,
                                                    const float* __restrict__ w2e,
                                                    const float* __restrict__ lw,
                                                    float* __restrict__ out) {
    __shared__ float tE[808];   // even-t spikes: copy A @0, copy B @404
    __shared__ float tO[808];   // odd-t  spikes: same layout
    int lane = threadIdx.x;
    int b = blockIdx.x;

    #pragma unroll
    for (int k = 0; k < 13; ++k) {
        int i = lane + k * 64;
        if (i < 808) { tE[i] = 0.f; tO[i] = 0.f; }
    }

    // stage-1 mapping: f = 64k + lane -> (ch=k, r=lane>>3, c=lane&7)
    int r1 = lane >> 3, c1 = lane & 7;
    int posq = ((r1 + 1) * 10 + (c1 + 1)) * 4;
    float* wE0 = &tE[posq];
    float* wE1 = &tE[404 + posq];
    float* wO0 = &tO[posq];
    float* wO1 = &tO[404 + posq];

    // conv2 mapping: f2a = lane -> (oc, p, q); f2b = lane + 64 -> oc+4 same (p,q)
    int oc = lane >> 4, p = (lane >> 2) & 3, q = lane & 3;

    // conv2 weights resident in VGPRs
    float wa[64], wb[64];
    #pragma unroll
    for (int k = 0; k < 16; ++k) {
        float4 ta = *(const float4*)(w2e + oc * 64 + k * 4);
        float4 tb = *(const float4*)(w2e + (oc + 4) * 64 + k * 4);
        wa[k * 4 + 0] = ta.x; wa[k * 4 + 1] = ta.y; wa[k * 4 + 2] = ta.z; wa[k * 4 + 3] = ta.w;
        wb[k * 4 + 0] = tb.x; wb[k * 4 + 1] = tb.y; wb[k * 4 + 2] = tb.z; wb[k * 4 + 3] = tb.w;
    }

    int rbq = ((2 * p) * 10 + 2 * q) * 4 + ((p & 1) ? 404 : 0);
    const float* rbE = &tE[rbq];
    const float* rbO = &tO[rbq];

    float lw0a = lw[lane],       lw0b = lw[lane + 64];
    float lw1a = lw[lane + 128], lw1b = lw[lane + 192];

    const float* src = y1 + (long)b * 25600 + lane;   // y1[b][t][f], f = 64k+lane
    float* outp = out + (long)b * 200;

    // prologue loads: t=0 (consumed now) + pipeline stages t=1..4
    float x0  = src[0],    x1  = src[64],   x2  = src[128],  x3  = src[192];
    float c10 = src[256],  c11 = src[320],  c12 = src[384],  c13 = src[448];
    float c20 = src[512],  c21 = src[576],  c22 = src[640],  c23 = src[704];
    float p10 = src[768],  p11 = src[832],  p12 = src[896],  p13 = src[960];
    float p20 = src[1024], p21 = src[1088], p22 = src[1152], p23 = src[1216];

    float v10 = 0.f, v20 = 0.f, v11 = 0.f, v21 = 0.f;
    float v12 = 0.f, v22 = 0.f, v13 = 0.f, v23 = 0.f;
    float w1a = 0.f, w2a = 0.f, w1b = 0.f, w2b = 0.f;

    // scan1(t=0) -> write E
    {
        v10 = ALPHA * v10 + x0; v20 = ALPHA * v20 + v10;
        float s0 = (v20 >= 1.f) ? 1.f : 0.f; v20 -= s0;
        v11 = ALPHA * v11 + x1; v21 = ALPHA * v21 + v11;
        float s1 = (v21 >= 1.f) ? 1.f : 0.f; v21 -= s1;
        v12 = ALPHA * v12 + x2; v22 = ALPHA * v22 + v12;
        float s2 = (v22 >= 1.f) ? 1.f : 0.f; v22 -= s2;
        v13 = ALPHA * v13 + x3; v23 = ALPHA * v23 + v13;
        float s3 = (v23 >= 1.f) ? 1.f : 0.f; v23 -= s3;
        float4 sp = make_float4(s0, s1, s2, s3);
        *(float4*)wE0 = sp;
        *(float4*)wE1 = sp;
    }

    for (int i = 0; i < 49; ++i) {
        // ---- deep prefetch: t = 2i+5, 2i+6 (consumed 2 iterations later) ----
        int t5 = 2 * i + 5, t6 = 2 * i + 6;
        const float* a5 = src + (t5 < 100 ? t5 * 256 : 0);
        const float* a6 = src + (t6 < 100 ? t6 * 256 : 0);
        float n10 = a5[0], n11 = a5[64], n12 = a5[128], n13 = a5[192];
        float n20 = a6[0], n21 = a6[64], n22 = a6[128], n23 = a6[192];

        // ---- read window for even t=2i from E (written last iteration) ----
        float qa[64];
        #pragma unroll
        for (int rr = 0; rr < 4; ++rr) {
            #pragma unroll
            for (int cc = 0; cc < 4; ++cc) {
                float4 tq = *(const float4*)(rbE + rr * 40 + cc * 4);
                int o = (rr * 4 + cc) * 4;
                qa[o + 0] = tq.x; qa[o + 1] = tq.y; qa[o + 2] = tq.z; qa[o + 3] = tq.w;
            }
        }

        // ---- scan1(2i+1) -> write O (overlaps qa read returns) ----
        v10 = ALPHA * v10 + c10; v20 = ALPHA * v20 + v10;
        float sA0 = (v20 >= 1.f) ? 1.f : 0.f; v20 -= sA0;
        v11 = ALPHA * v11 + c11; v21 = ALPHA * v21 + v11;
        float sA1 = (v21 >= 1.f) ? 1.f : 0.f; v21 -= sA1;
        v12 = ALPHA * v12 + c12; v22 = ALPHA * v22 + v12;
        float sA2 = (v22 >= 1.f) ? 1.f : 0.f; v22 -= sA2;
        v13 = ALPHA * v13 + c13; v23 = ALPHA * v23 + v13;
        float sA3 = (v23 >= 1.f) ? 1.f : 0.f; v23 -= sA3;
        float4 spA = make_float4(sA0, sA1, sA2, sA3);
        *(float4*)wO0 = spA;
        *(float4*)wO1 = spA;

        // ---- conv FMA for t=2i (ch-major, bit-exact chain) + scan2 ----
        float accaE = 0.f, accbE = 0.f;
        #pragma unroll
        for (int ch = 0; ch < 4; ++ch)
            #pragma unroll
            for (int rr = 0; rr < 4; ++rr)
                #pragma unroll
                for (int cc = 0; cc < 4; ++cc) {
                    float xv = qa[(rr * 4 + cc) * 4 + ch];
                    accaE += wa[ch * 16 + rr * 4 + cc] * xv;
                    accbE += wb[ch * 16 + rr * 4 + cc] * xv;
                }
        w1a = ALPHA * w1a + accaE; w2a = ALPHA * w2a + w1a;
        float saE = (w2a >= 1.f) ? 1.f : 0.f; w2a -= saE;
        w1b = ALPHA * w1b + accbE; w2b = ALPHA * w2b + w1b;
        float sbE = (w2b >= 1.f) ? 1.f : 0.f; w2b -= sbE;

        // ---- read window for odd t=2i+1 from O (write ~300 cyc old) ----
        float qb[64];
        #pragma unroll
        for (int rr = 0; rr < 4; ++rr) {
            #pragma unroll
            for (int cc = 0; cc < 4; ++cc) {
                float4 tq = *(const float4*)(rbO + rr * 40 + cc * 4);
                int o = (rr * 4 + cc) * 4;
                qb[o + 0] = tq.x; qb[o + 1] = tq.y; qb[o + 2] = tq.z; qb[o + 3] = tq.w;
            }
        }

        // ---- scan1(2i+2) -> write E (reads of E already issued: WAR safe) ----
        v10 = ALPHA * v10 + c20; v20 = ALPHA * v20 + v10;
        float sB0 = (v20 >= 1.f) ? 1.f : 0.f; v20 -= sB0;
        v11 = ALPHA * v11 + c21; v21 = ALPHA * v21 + v11;
        float sB1 = (v21 >= 1.f) ? 1.f : 0.f; v21 -= sB1;
        v12 = ALPHA * v12 + c22; v22 = ALPHA * v22 + v12;
        float sB2 = (v22 >= 1.f) ? 1.f : 0.f; v22 -= sB2;
        v13 = ALPHA * v13 + c23; v23 = ALPHA * v23 + v13;
        float sB3 = (v23 >= 1.f) ? 1.f : 0.f; v23 -= sB3;
        float4 spB = make_float4(sB0, sB1, sB2, sB3);
        *(float4*)wE0 = spB;
        *(float4*)wE1 = spB;

        // ---- conv FMA for t=2i+1 + scan2 ----
        float accaO = 0.f, accbO = 0.f;
        #pragma unroll
        for (int ch = 0; ch < 4; ++ch)
            #pragma unroll
            for (int rr = 0; rr < 4; ++rr)
                #pragma unroll
                for (int cc = 0; cc < 4; ++cc) {
                    float xv = qb[(rr * 4 + cc) * 4 + ch];
                    accaO += wa[ch * 16 + rr * 4 + cc] * xv;
                    accbO += wb[ch * 16 + rr * 4 + cc] * xv;
                }
        w1a = ALPHA * w1a + accaO; w2a = ALPHA * w2a + w1a;
        float saO = (w2a >= 1.f) ? 1.f : 0.f; w2a -= saO;
        w1b = ALPHA * w1b + accbO; w2b = ALPHA * w2b + w1b;
        float sbO = (w2b >= 1.f) ? 1.f : 0.f; w2b -= sbO;

        // ---- linear tail for (2i, 2i+1): same xor tree as before ----
        float a0 = saE * lw0a + sbE * lw0b;
        float a1 = saE * lw1a + sbE * lw1b;
        float b0 = saO * lw0a + sbO * lw0b;
        float b1 = saO * lw1a + sbO * lw1b;
        #pragma unroll
        for (int off = 32; off; off >>= 1) {
            a0 += __shfl_xor(a0, off);
            a1 += __shfl_xor(a1, off);
            b0 += __shfl_xor(b0, off);
            b1 += __shfl_xor(b1, off);
        }
        if (lane == 0) {
            *(float2*)(outp + 4 * i)     = make_float2(a0, a1);
            *(float2*)(outp + 4 * i + 2) = make_float2(b0, b1);
        }

        // ---- rotate y1 pipeline ----
        c10 = p10; c11 = p11; c12 = p12; c13 = p13;
        c20 = p20; c21 = p21; c22 = p22; c23 = p23;
        p10 = n10; p11 = n11; p12 = n12; p13 = n13;
        p20 = n20; p21 = n21; p22 = n22; p23 = n23;
    }

    // ---- epilogue: conv(98) from E, scan1(99)->O, conv(99) from O ----
    {
        float qa[64];
        #pragma unroll
        for (int rr = 0; rr < 4; ++rr) {
            #pragma unroll
            for (int cc = 0; cc < 4; ++cc) {
                float4 tq = *(const float4*)(rbE + rr * 40 + cc * 4);
                int o = (rr * 4 + cc) * 4;
                qa[o + 0] = tq.x; qa[o + 1] = tq.y; qa[o + 2] = tq.z; qa[o + 3] = tq.w;
            }
        }

        // scan1(99): c1 now holds y1[99]
        v10 = ALPHA * v10 + c10; v20 = ALPHA * v20 + v10;
        float sA0 = (v20 >= 1.f) ? 1.f : 0.f; v20 -= sA0;
        v11 = ALPHA * v11 + c11; v21 = ALPHA * v21 + v11;
        float sA1 = (v21 >= 1.f) ? 1.f : 0.f; v21 -= sA1;
        v12 = ALPHA * v12 + c12; v22 = ALPHA * v22 + v12;
        float sA2 = (v22 >= 1.f) ? 1.f : 0.f; v22 -= sA2;
        v13 = ALPHA * v13 + c13; v23 = ALPHA * v23 + v13;
        float sA3 = (v23 >= 1.f) ? 1.f : 0.f; v23 -= sA3;
        float4 spA = make_float4(sA0, sA1, sA2, sA3);
        *(float4*)wO0 = spA;
        *(float4*)wO1 = spA;

        // conv(98)
        float accaE = 0.f, accbE = 0.f;
        #pragma unroll
        for (int ch = 0; ch < 4; ++ch)
            #pragma unroll
            for (int rr = 0; rr < 4; ++rr)
                #pragma unroll
                for (int cc = 0; cc < 4; ++cc) {
                    float xv = qa[(rr * 4 + cc) * 4 + ch];
                    accaE += wa[ch * 16 + rr * 4 + cc] * xv;
                    accbE += wb[ch * 16 + rr * 4 + cc] * xv;
                }
        w1a = ALPHA * w1a + accaE; w2a = ALPHA * w2a + w1a;
        float saE = (w2a >= 1.f) ? 1.f : 0.f; w2a -= saE;
        w1b = ALPHA * w1b + accbE; w2b = ALPHA * w2b + w1b;
        float sbE = (w2b >= 1.f) ? 1.f : 0.f; w2b -= sbE;

        // conv(99)
        float qb[64];
        #pragma unroll
        for (int rr = 0; rr < 4; ++rr) {
            #pragma unroll
            for (int cc = 0; cc < 4; ++cc) {
                float4 tq = *(const float4*)(rbO + rr * 40 + cc * 4);
                int o = (rr * 4 + cc) * 4;
                qb[o + 0] = tq.x; qb[o + 1] = tq.y; qb[o + 2] = tq.z; qb[o + 3] = tq.w;
            }
        }
        float accaO = 0.f, accbO = 0.f;
        #pragma unroll
        for (int ch = 0; ch < 4; ++ch)
            #pragma unroll
            for (int rr = 0; rr < 4; ++rr)
                #pragma unroll
                for (int cc = 0; cc < 4; ++cc) {
                    float xv = qb[(rr * 4 + cc) * 4 + ch];
                    accaO += wa[ch * 16 + rr * 4 + cc] * xv;
                    accbO += wb[ch * 16 + rr * 4 + cc] * xv;
                }
        w1a = ALPHA * w1a + accaO; w2a = ALPHA * w2a + w1a;
        float saO = (w2a >= 1.f) ? 1.f : 0.f; w2a -= saO;
        w1b = ALPHA * w1b + accbO; w2b = ALPHA * w2b + w1b;
        float sbO = (w2b >= 1.f) ? 1.f : 0.f; w2b -= sbO;

        float a0 = saE * lw0a + sbE * lw0b;
        float a1 = saE * lw1a + sbE * lw1b;
        float b0 = saO * lw0a + sbO * lw0b;
        float b1 = saO * lw1a + sbO * lw1b;
        #pragma unroll
        for (int off = 32; off; off >>= 1) {
            a0 += __shfl_xor(a0, off);
            a1 += __shfl_xor(a1, off);
            b0 += __shfl_xor(b0, off);
            b1 += __shfl_xor(b1, off);
        }
        if (lane == 0) {
            *(float2*)(outp + 196) = make_float2(a0, a1);
            *(float2*)(outp + 198) = make_float2(b0, b1);
        }
    }
}

extern "C" void kernel_launch(void* const* d_in, const int* in_sizes, int n_in,
                              void* d_out, int out_size, void* d_ws, size_t ws_size,
                              hipStream_t stream) {
    const float* x  = (const float*)d_in[0];   // [128,100,2,32,32]
    const float* w1 = (const float*)d_in[1];   // [4,2,5,5]
    const float* w2 = (const float*)d_in[2];   // [8,4,3,3]
    const float* lw = (const float*)d_in[3];   // [2,128]
    float* out = (float*)d_out;                // [128,100,2]

    float* ws   = (float*)d_ws;
    float* w1e  = ws;                          // 512 floats
    float* w2e  = ws + 512;                    // 512 floats
    float* y1   = ws + 1024;                   // 12800*256 floats = 13.1 MB

    prep_weights<<<4, 256, 0, stream>>>(w1, w2, w1e, w2e);
    conv1_pool<<<3200, 256, 0, stream>>>(x, w1e, y1);
    fused_wave<<<128, 64, 0, stream>>>(y1, w2e, lw, out);
}